// Round 3
// baseline (546.280 us; speedup 1.0000x reference)
//
#include <hip/hip_runtime.h>
#include <math.h>

// Problem constants
#define BATCH 4
#define SEQ   4096
#define DIM   2048
#define DS    64
#define NF    4096
#define NR    2048
#define NT    2048
#define NTOT  8192          // NF+NR+NT
#define TOK   16384         // BATCH*SEQ

static __device__ __forceinline__ unsigned short f2bf(float x) {
  unsigned int u = __float_as_uint(x);
  u += 0x7fffu + ((u >> 16) & 1u);       // round-to-nearest-even
  return (unsigned short)(u >> 16);
}
static __device__ __forceinline__ float bf2f(unsigned int lo16) {
  return __uint_as_float(lo16 << 16);
}

// ---------------------------------------------------------------------------
// K0: per-neuron reciprocal norm: scale[n] = 1/max(||emb_n||, 1e-12)
// ---------------------------------------------------------------------------
__global__ __launch_bounds__(256) void k_norm(const float* __restrict__ emb,
                                              float* __restrict__ scale) {
  int row  = blockIdx.x * 4 + (threadIdx.x >> 6);
  int lane = threadIdx.x & 63;
  float v  = emb[(size_t)row * DS + lane];
  float ss = v * v;
#pragma unroll
  for (int m = 32; m >= 1; m >>= 1) ss += __shfl_xor(ss, m, 64);
  if (lane == 0) scale[row] = 1.0f / fmaxf(sqrtf(ss), 1e-12f);
}

// ---------------------------------------------------------------------------
// K1: h = x @ W + b    (M=16384, K=2048, N=64)
// ---------------------------------------------------------------------------
__global__ __launch_bounds__(256) void k_h(const float* __restrict__ x,
                                           const float* __restrict__ W,
                                           const float* __restrict__ bias,
                                           float* __restrict__ h) {
  __shared__ float xs[64 * 36];   // [t][36] padded rows
  __shared__ float wt[32 * 64];   // [dd][c]
  const int tid = threadIdx.x;
  const int t0  = blockIdx.x * 64;
  const int cg  = tid & 7;
  const int tg  = tid >> 3;       // 0..31
  const int c8  = cg * 8;

  float acc[2][8];
#pragma unroll
  for (int j = 0; j < 2; ++j)
#pragma unroll
    for (int c = 0; c < 8; ++c) acc[j][c] = 0.0f;

  for (int d0 = 0; d0 < DIM; d0 += 32) {
    __syncthreads();
#pragma unroll
    for (int k = 0; k < 2; ++k) {
      int idx = tid + k * 256;
      int t = idx >> 3, dd4 = idx & 7;
      float4 v = *reinterpret_cast<const float4*>(
          &x[(size_t)(t0 + t) * DIM + d0 + dd4 * 4]);
      *reinterpret_cast<float4*>(&xs[t * 36 + dd4 * 4]) = v;
    }
#pragma unroll
    for (int k = 0; k < 2; ++k) {
      int idx = tid + k * 256;
      int d = idx >> 4, cq = idx & 15;
      float4 v = *reinterpret_cast<const float4*>(
          &W[(size_t)(d0 + d) * DS + cq * 4]);
      *reinterpret_cast<float4*>(&wt[d * 64 + cq * 4]) = v;
    }
    __syncthreads();

#pragma unroll
    for (int dd4 = 0; dd4 < 8; ++dd4) {
      float4 xa4 = *reinterpret_cast<const float4*>(&xs[tg * 36 + dd4 * 4]);
      float4 xb4 = *reinterpret_cast<const float4*>(&xs[(tg + 32) * 36 + dd4 * 4]);
      float xa[4] = {xa4.x, xa4.y, xa4.z, xa4.w};
      float xb[4] = {xb4.x, xb4.y, xb4.z, xb4.w};
#pragma unroll
      for (int dd = 0; dd < 4; ++dd) {
        float4 w0 = *reinterpret_cast<const float4*>(&wt[(dd4 * 4 + dd) * 64 + c8]);
        float4 w1 = *reinterpret_cast<const float4*>(&wt[(dd4 * 4 + dd) * 64 + c8 + 4]);
        acc[0][0] += xa[dd] * w0.x;  acc[0][1] += xa[dd] * w0.y;
        acc[0][2] += xa[dd] * w0.z;  acc[0][3] += xa[dd] * w0.w;
        acc[0][4] += xa[dd] * w1.x;  acc[0][5] += xa[dd] * w1.y;
        acc[0][6] += xa[dd] * w1.z;  acc[0][7] += xa[dd] * w1.w;
        acc[1][0] += xb[dd] * w0.x;  acc[1][1] += xb[dd] * w0.y;
        acc[1][2] += xb[dd] * w0.z;  acc[1][3] += xb[dd] * w0.w;
        acc[1][4] += xb[dd] * w1.x;  acc[1][5] += xb[dd] * w1.y;
        acc[1][6] += xb[dd] * w1.z;  acc[1][7] += xb[dd] * w1.w;
      }
    }
  }

  float bl[8];
#pragma unroll
  for (int c = 0; c < 8; ++c) bl[c] = bias[c8 + c];
#pragma unroll
  for (int j = 0; j < 2; ++j) {
    int t = t0 + tg + 32 * j;
    float4 o0, o1;
    o0.x = acc[j][0] + bl[0]; o0.y = acc[j][1] + bl[1];
    o0.z = acc[j][2] + bl[2]; o0.w = acc[j][3] + bl[3];
    o1.x = acc[j][4] + bl[4]; o1.y = acc[j][5] + bl[5];
    o1.z = acc[j][6] + bl[6]; o1.w = acc[j][7] + bl[7];
    *reinterpret_cast<float4*>(&h[(size_t)t * DS + c8]) = o0;
    *reinterpret_cast<float4*>(&h[(size_t)t * DS + c8 + 4]) = o1;
  }
}

// ---------------------------------------------------------------------------
// K2: tiled logits GEMM (16384 x 8192 x K=64) with fused epilogues.
// tile: 128 tokens x 128 neurons, 256 threads, 8x8 register blocking.
// LDS: both tiles staged transposed (k-major). emb pre-scaled by 1/||emb||.
// MODE 0: Zp[t][cb] = row-sum of exp(logits)           (per 128-neuron block)
// MODE 1: MODE 0 + store E = exp(logits) as bf16
// MODE 2: Bp[tb][n] = sum_i a[sl][t_i] * exp(logits)   (pooled partials)
// ---------------------------------------------------------------------------
template<int MODE>
__global__ __launch_bounds__(256) void k_logits(
    const float* __restrict__ h, const float* __restrict__ emb,
    const float* __restrict__ scale, const float* __restrict__ a,
    float* __restrict__ Zp, unsigned short* __restrict__ E,
    float* __restrict__ Bp) {
  __shared__ float hs[64 * 128];   // [k][token]
  __shared__ float es[64 * 128];   // [k][neuron]  (pre-scaled)
  const int tid = threadIdx.x;
  const int tb  = blockIdx.x;          // token block 0..127
  const int cb  = blockIdx.y;          // neuron block 0..63
  const int t0  = tb * 128;
  const int n0  = cb * 128;

  // stage both tiles, transposed
#pragma unroll
  for (int it = 0; it < 8; ++it) {
    int idx = tid + it * 256;          // 0..2047
    int r = idx >> 4, dq = idx & 15;
    float4 v = *reinterpret_cast<const float4*>(&h[(size_t)(t0 + r) * DS + dq * 4]);
    hs[(dq * 4 + 0) * 128 + r] = v.x;
    hs[(dq * 4 + 1) * 128 + r] = v.y;
    hs[(dq * 4 + 2) * 128 + r] = v.z;
    hs[(dq * 4 + 3) * 128 + r] = v.w;
    float sc = scale[n0 + r];
    float4 w = *reinterpret_cast<const float4*>(&emb[(size_t)(n0 + r) * DS + dq * 4]);
    es[(dq * 4 + 0) * 128 + r] = w.x * sc;
    es[(dq * 4 + 1) * 128 + r] = w.y * sc;
    es[(dq * 4 + 2) * 128 + r] = w.z * sc;
    es[(dq * 4 + 3) * 128 + r] = w.w * sc;
  }
  __syncthreads();

  const int tx = tid & 15;             // neuron groups
  const int ty = tid >> 4;             // token group
  float acc[8][8];
#pragma unroll
  for (int i = 0; i < 8; ++i)
#pragma unroll
    for (int j = 0; j < 8; ++j) acc[i][j] = 0.0f;

#pragma unroll 2
  for (int k = 0; k < 64; ++k) {
    const float* hr = &hs[k * 128 + ty * 8];
    const float* er = &es[k * 128 + tx * 4];
    float4 a0 = *reinterpret_cast<const float4*>(hr);
    float4 a1 = *reinterpret_cast<const float4*>(hr + 4);
    float4 b0 = *reinterpret_cast<const float4*>(er);
    float4 b1 = *reinterpret_cast<const float4*>(er + 64);
    float av[8] = {a0.x, a0.y, a0.z, a0.w, a1.x, a1.y, a1.z, a1.w};
    float bv[8] = {b0.x, b0.y, b0.z, b0.w, b1.x, b1.y, b1.z, b1.w};
#pragma unroll
    for (int i = 0; i < 8; ++i)
#pragma unroll
      for (int j = 0; j < 8; ++j) acc[i][j] = fmaf(av[i], bv[j], acc[i][j]);
  }
  // thread's neurons: col(j) = tx*4+j (j<4), 64+tx*4+j-4 (j>=4)

  if (MODE == 2) {
    const int sl = (cb < 32) ? 0 : ((cb < 48) ? 1 : 2);
    float av8[8];
#pragma unroll
    for (int i = 0; i < 8; ++i) av8[i] = a[(size_t)sl * TOK + t0 + ty * 8 + i];
    float cs[8];
#pragma unroll
    for (int j = 0; j < 8; ++j) {
      float s = 0.0f;
#pragma unroll
      for (int i = 0; i < 8; ++i) s = fmaf(av8[i], __expf(acc[i][j]), s);
      cs[j] = s;
    }
    __syncthreads();
    float* red = hs;                   // reuse as [16][128]
#pragma unroll
    for (int j = 0; j < 8; ++j) {
      int c = (j < 4) ? (tx * 4 + j) : (64 + tx * 4 + (j - 4));
      red[ty * 128 + c] = cs[j];
    }
    __syncthreads();
    if (tid < 128) {
      float v = 0.0f;
#pragma unroll
      for (int yy = 0; yy < 16; ++yy) v += red[yy * 128 + tid];
      Bp[(size_t)tb * NTOT + n0 + tid] = v;
    }
  } else {
    float rs[8];
#pragma unroll
    for (int i = 0; i < 8; ++i) {
      float s = 0.0f;
#pragma unroll
      for (int j = 0; j < 8; ++j) {
        acc[i][j] = __expf(acc[i][j]);
        s += acc[i][j];
      }
      rs[i] = s;
    }
#pragma unroll
    for (int m = 1; m < 16; m <<= 1)
#pragma unroll
      for (int i = 0; i < 8; ++i) rs[i] += __shfl_xor(rs[i], m, 64);
    if (tx == 0) {
#pragma unroll
      for (int i = 0; i < 8; ++i)
        Zp[(size_t)(t0 + ty * 8 + i) * 64 + cb] = rs[i];
    }
    if (MODE == 1) {
#pragma unroll
      for (int i = 0; i < 8; ++i) {
        size_t row = (size_t)(t0 + ty * 8 + i) * NTOT;
        uint2 w0, w1;
        w0.x = (unsigned)f2bf(acc[i][0]) | ((unsigned)f2bf(acc[i][1]) << 16);
        w0.y = (unsigned)f2bf(acc[i][2]) | ((unsigned)f2bf(acc[i][3]) << 16);
        w1.x = (unsigned)f2bf(acc[i][4]) | ((unsigned)f2bf(acc[i][5]) << 16);
        w1.y = (unsigned)f2bf(acc[i][6]) | ((unsigned)f2bf(acc[i][7]) << 16);
        *reinterpret_cast<uint2*>(&E[row + n0 + tx * 4]) = w0;
        *reinterpret_cast<uint2*>(&E[row + n0 + 64 + tx * 4]) = w1;
      }
    }
  }
}

// ---------------------------------------------------------------------------
// K3: combine 64 Zp partials per token into a[slice][t] = imp_t / Z_slice
// ---------------------------------------------------------------------------
__global__ __launch_bounds__(256) void k_a2(const float* __restrict__ Zp,
                                            const float* __restrict__ imp,
                                            float* __restrict__ a) {
  int t = blockIdx.x * 256 + threadIdx.x;
  const float4* zp = reinterpret_cast<const float4*>(&Zp[(size_t)t * 64]);
  float zf = 0.f, zr = 0.f, zt = 0.f;
#pragma unroll
  for (int q = 0; q < 8; ++q)  { float4 v = zp[q]; zf += (v.x + v.y) + (v.z + v.w); }
#pragma unroll
  for (int q = 8; q < 12; ++q) { float4 v = zp[q]; zr += (v.x + v.y) + (v.z + v.w); }
#pragma unroll
  for (int q = 12; q < 16; ++q){ float4 v = zp[q]; zt += (v.x + v.y) + (v.z + v.w); }
  float im = imp[t];
  a[t]           = im / zf;
  a[TOK + t]     = im / zr;
  a[2 * TOK + t] = im / zt;
}

// ---------------------------------------------------------------------------
// K4 (E-path): pooled partials from stored E. Streaming, memory-bound.
// grid (16 nblocks x 8 tchunks x 4 batches), 256 thr, 2 neurons/thread.
// ---------------------------------------------------------------------------
__global__ __launch_bounds__(256) void k_poolE(const unsigned short* __restrict__ E,
                                               const float* __restrict__ a,
                                               float* __restrict__ Bp) {
  const int nb = blockIdx.x;          // 0..15
  const int tb = blockIdx.y;          // 0..7
  const int b  = blockIdx.z;          // 0..3
  const int n2 = nb * 512 + threadIdx.x * 2;
  const int sl = (n2 < NF) ? 0 : ((n2 < NF + NR) ? 1 : 2);
  const float* ap = a + (size_t)sl * TOK + b * SEQ + tb * 512;
  const unsigned short* ep = E + (size_t)(b * SEQ + tb * 512) * NTOT + n2;
  float acc0 = 0.f, acc1 = 0.f;
#pragma unroll 4
  for (int s = 0; s < 512; ++s) {
    unsigned int w = *reinterpret_cast<const unsigned int*>(ep + (size_t)s * NTOT);
    float at = ap[s];
    acc0 = fmaf(at, bf2f(w & 0xffffu), acc0);
    acc1 = fmaf(at, bf2f(w >> 16), acc1);
  }
  float* o = Bp + (size_t)(b * 8 + tb) * NTOT + n2;
  o[0] = acc0; o[1] = acc1;
}

// ---------------------------------------------------------------------------
// K5: per (batch, slice): reduce G partials, top-k, renorm, scatter.
// ---------------------------------------------------------------------------
__global__ __launch_bounds__(256) void k_topk(const float* __restrict__ Bp,
                                              float* __restrict__ out, int G) {
  __shared__ float p[4096];
  __shared__ float rv[256];
  __shared__ int   ri[256];
  __shared__ float vals[8];
  __shared__ int   idxs[8];
  __shared__ float s_inv;

  const int bid = blockIdx.x;
  const int b   = bid / 3;
  const int sl  = bid % 3;
  const int off = (sl == 0) ? 0 : ((sl == 1) ? NF : NF + NR);
  const int N   = (sl == 0) ? NF : NR;
  const int K   = (sl == 0) ? 8 : ((sl == 1) ? 4 : 6);
  const int tid = threadIdx.x;

  for (int i = tid; i < N; i += 256) {
    float v = 0.0f;
    for (int g = 0; g < G; ++g)
      v += Bp[((size_t)(b * G + g)) * NTOT + off + i];
    p[i] = v;
  }
  __syncthreads();

  for (int k = 0; k < K; ++k) {
    float bv = -2.0f;
    int bi = 1 << 30;
    for (int i = tid; i < N; i += 256) {
      float v = p[i];
      if (v > bv) { bv = v; bi = i; }
    }
    rv[tid] = bv; ri[tid] = bi;
    __syncthreads();
    for (int st = 128; st > 0; st >>= 1) {
      if (tid < st) {
        float v2 = rv[tid + st]; int i2 = ri[tid + st];
        if (v2 > rv[tid] || (v2 == rv[tid] && i2 < ri[tid])) {
          rv[tid] = v2; ri[tid] = i2;
        }
      }
      __syncthreads();
    }
    if (tid == 0) {
      vals[k] = rv[0]; idxs[k] = ri[0];
      p[ri[0]] = -1.0f;
    }
    __syncthreads();
  }

  if (tid == 0) {
    float s = 0.0f;
    for (int k = 0; k < K; ++k) s += vals[k];
    s_inv = 1.0f / (s + 1e-8f);
  }
  __syncthreads();

  float* ob = out + (size_t)b * (NF + 2 * NR + NT);
  if (sl == 0) {
    for (int i = tid; i < NF; i += 256) ob[i] = 0.0f;
  } else if (sl == 1) {
    for (int i = tid; i < NR; i += 256) { ob[NF + i] = 0.0f; ob[NF + NR + i] = 0.0f; }
  } else {
    for (int i = tid; i < NT; i += 256) ob[NF + 2 * NR + i] = 0.0f;
  }
  __syncthreads();
  if (tid < K) {
    float v = vals[tid] * s_inv;
    int ix = idxs[tid];
    if (sl == 0) {
      ob[ix] = v;
    } else if (sl == 1) {
      ob[NF + ix] = v;
      ob[NF + NR + ix] = v;
    } else {
      ob[NF + 2 * NR + ix] = v;
    }
  }
}

// ---------------------------------------------------------------------------
extern "C" void kernel_launch(void* const* d_in, const int* in_sizes, int n_in,
                              void* d_out, int out_size, void* d_ws, size_t ws_size,
                              hipStream_t stream) {
  const float* x    = (const float*)d_in[0];   // [B,S,D]
  const float* imp  = (const float*)d_in[1];   // [B,S]
  const float* W    = (const float*)d_in[2];   // [D,DS]
  const float* bias = (const float*)d_in[3];   // [DS]
  const float* emb  = (const float*)d_in[4];   // [NTOT,DS]
  float* out = (float*)d_out;
  float* ws  = (float*)d_ws;

  // workspace layout (floats)
  float* scale = ws;                             // 8192
  float* h     = scale + NTOT;                   // TOK*64
  float* Zp    = h + (size_t)TOK * DS;           // TOK*64
  float* a     = Zp + (size_t)TOK * 64;          // 3*TOK
  float* Bp    = a + 3 * TOK;                    // 128*NTOT (max)
  unsigned short* E = (unsigned short*)(Bp + (size_t)128 * NTOT);

  size_t base_f    = (size_t)NTOT + (size_t)TOK * DS + (size_t)TOK * 64 +
                     3 * (size_t)TOK + (size_t)128 * NTOT;
  size_t need_base = base_f * sizeof(float);                       // ~12.8 MB
  size_t need_E    = need_base + (size_t)TOK * NTOT * 2;           // +268 MB
  if (ws_size < need_base) return;
  const bool useE = (ws_size >= need_E);

  k_norm<<<NTOT / 4, 256, 0, stream>>>(emb, scale);
  k_h<<<TOK / 64, 256, 0, stream>>>(x, W, bias, h);

  if (useE) {
    k_logits<1><<<dim3(128, 64), 256, 0, stream>>>(h, emb, scale, nullptr, Zp, E, nullptr);
    k_a2<<<TOK / 256, 256, 0, stream>>>(Zp, imp, a);
    k_poolE<<<dim3(16, 8, 4), 256, 0, stream>>>(E, a, Bp);
    k_topk<<<12, 256, 0, stream>>>(Bp, out, 8);
  } else {
    k_logits<0><<<dim3(128, 64), 256, 0, stream>>>(h, emb, scale, nullptr, Zp, nullptr, nullptr);
    k_a2<<<TOK / 256, 256, 0, stream>>>(Zp, imp, a);
    k_logits<2><<<dim3(128, 64), 256, 0, stream>>>(h, emb, scale, a, nullptr, nullptr, Bp);
    k_topk<<<12, 256, 0, stream>>>(Bp, out, 32);
  }
}

// Round 4
// 423.156 us; speedup vs baseline: 1.2910x; 1.2910x over previous
//
#include <hip/hip_runtime.h>
#include <math.h>

// Problem constants
#define BATCH 4
#define SEQ   4096
#define DIM   2048
#define DS    64
#define NF    4096
#define NR    2048
#define NT    2048
#define NTOT  8192          // NF+NR+NT
#define TOK   16384         // BATCH*SEQ

typedef __attribute__((ext_vector_type(8))) __bf16 bf16x8;
typedef __attribute__((ext_vector_type(4))) float  f32x4;

static __device__ __forceinline__ unsigned short f2bf(float x) {
  unsigned int u = __float_as_uint(x);
  u += 0x7fffu + ((u >> 16) & 1u);       // round-to-nearest-even
  return (unsigned short)(u >> 16);
}
static __device__ __forceinline__ float bf2f(unsigned int lo16) {
  return __uint_as_float(lo16 << 16);
}

// ---------------------------------------------------------------------------
// K0: per-neuron reciprocal norm: scale[n] = 1/max(||emb_n||, 1e-12)
// ---------------------------------------------------------------------------
__global__ __launch_bounds__(256) void k_norm(const float* __restrict__ emb,
                                              float* __restrict__ scale) {
  int row  = blockIdx.x * 4 + (threadIdx.x >> 6);
  int lane = threadIdx.x & 63;
  float v  = emb[(size_t)row * DS + lane];
  float ss = v * v;
#pragma unroll
  for (int m = 32; m >= 1; m >>= 1) ss += __shfl_xor(ss, m, 64);
  if (lane == 0) scale[row] = 1.0f / fmaxf(sqrtf(ss), 1e-12f);
}

// ---------------------------------------------------------------------------
// K1: h = x @ W + b    (M=16384, K=2048, N=64)  — f32 vector GEMM
// ---------------------------------------------------------------------------
__global__ __launch_bounds__(256) void k_h(const float* __restrict__ x,
                                           const float* __restrict__ W,
                                           const float* __restrict__ bias,
                                           float* __restrict__ h) {
  __shared__ float xs[64 * 36];   // [t][36] padded rows
  __shared__ float wt[32 * 64];   // [dd][c]
  const int tid = threadIdx.x;
  const int t0  = blockIdx.x * 64;
  const int cg  = tid & 7;
  const int tg  = tid >> 3;       // 0..31
  const int c8  = cg * 8;

  float acc[2][8];
#pragma unroll
  for (int j = 0; j < 2; ++j)
#pragma unroll
    for (int c = 0; c < 8; ++c) acc[j][c] = 0.0f;

  for (int d0 = 0; d0 < DIM; d0 += 32) {
    __syncthreads();
#pragma unroll
    for (int k = 0; k < 2; ++k) {
      int idx = tid + k * 256;
      int t = idx >> 3, dd4 = idx & 7;
      float4 v = *reinterpret_cast<const float4*>(
          &x[(size_t)(t0 + t) * DIM + d0 + dd4 * 4]);
      *reinterpret_cast<float4*>(&xs[t * 36 + dd4 * 4]) = v;
    }
#pragma unroll
    for (int k = 0; k < 2; ++k) {
      int idx = tid + k * 256;
      int d = idx >> 4, cq = idx & 15;
      float4 v = *reinterpret_cast<const float4*>(
          &W[(size_t)(d0 + d) * DS + cq * 4]);
      *reinterpret_cast<float4*>(&wt[d * 64 + cq * 4]) = v;
    }
    __syncthreads();

#pragma unroll
    for (int dd4 = 0; dd4 < 8; ++dd4) {
      float4 xa4 = *reinterpret_cast<const float4*>(&xs[tg * 36 + dd4 * 4]);
      float4 xb4 = *reinterpret_cast<const float4*>(&xs[(tg + 32) * 36 + dd4 * 4]);
      float xa[4] = {xa4.x, xa4.y, xa4.z, xa4.w};
      float xb[4] = {xb4.x, xb4.y, xb4.z, xb4.w};
#pragma unroll
      for (int dd = 0; dd < 4; ++dd) {
        float4 w0 = *reinterpret_cast<const float4*>(&wt[(dd4 * 4 + dd) * 64 + c8]);
        float4 w1 = *reinterpret_cast<const float4*>(&wt[(dd4 * 4 + dd) * 64 + c8 + 4]);
        acc[0][0] += xa[dd] * w0.x;  acc[0][1] += xa[dd] * w0.y;
        acc[0][2] += xa[dd] * w0.z;  acc[0][3] += xa[dd] * w0.w;
        acc[0][4] += xa[dd] * w1.x;  acc[0][5] += xa[dd] * w1.y;
        acc[0][6] += xa[dd] * w1.z;  acc[0][7] += xa[dd] * w1.w;
        acc[1][0] += xb[dd] * w0.x;  acc[1][1] += xb[dd] * w0.y;
        acc[1][2] += xb[dd] * w0.z;  acc[1][3] += xb[dd] * w0.w;
        acc[1][4] += xb[dd] * w1.x;  acc[1][5] += xb[dd] * w1.y;
        acc[1][6] += xb[dd] * w1.z;  acc[1][7] += xb[dd] * w1.w;
      }
    }
  }

  float bl[8];
#pragma unroll
  for (int c = 0; c < 8; ++c) bl[c] = bias[c8 + c];
#pragma unroll
  for (int j = 0; j < 2; ++j) {
    int t = t0 + tg + 32 * j;
    float4 o0, o1;
    o0.x = acc[j][0] + bl[0]; o0.y = acc[j][1] + bl[1];
    o0.z = acc[j][2] + bl[2]; o0.w = acc[j][3] + bl[3];
    o1.x = acc[j][4] + bl[4]; o1.y = acc[j][5] + bl[5];
    o1.z = acc[j][6] + bl[6]; o1.w = acc[j][7] + bl[7];
    *reinterpret_cast<float4*>(&h[(size_t)t * DS + c8]) = o0;
    *reinterpret_cast<float4*>(&h[(size_t)t * DS + c8 + 4]) = o1;
  }
}

// ---------------------------------------------------------------------------
// K2: logits GEMM via split-bf16 MFMA (16384 x 8192, K=64), fused epilogues.
// tile: 128 tokens x 128 neurons, 256 thr (4 waves), wave = 32 tok x 128 n.
// a = a_hi + a_lo (bf16); A.B ~= Ah.Bh + Ah.Bl + Al.Bh  (3 MFMAs / k-half)
// LDS: [row][k] bf16, XOR-swizzled (byte ^= (row&7)<<4) -> conflict-free b128.
// MODE 0: Zp[t*64+cb] = sum_n exp(logit)   MODE 2: Bp[tb*NTOT+n] = sum_t a_t exp
// ---------------------------------------------------------------------------
template<int MODE>
__global__ __launch_bounds__(256) void k_zle(
    const float* __restrict__ h, const float* __restrict__ emb,
    const float* __restrict__ scale, const float* __restrict__ a,
    float* __restrict__ Zp, float* __restrict__ Bp) {
  __shared__ unsigned short hsh[128 * 64];   // 16 KB each
  __shared__ unsigned short hsl[128 * 64];
  __shared__ unsigned short esh[128 * 64];
  __shared__ unsigned short esl[128 * 64];
  const int tid = threadIdx.x;
  const int tb  = blockIdx.x;          // token block 0..127
  const int cb  = blockIdx.y;          // neuron block 0..63
  const int t0  = tb * 128;
  const int n0  = cb * 128;

  // ---- stage + split ----
#pragma unroll
  for (int it = 0; it < 8; ++it) {
    int idx = tid + it * 256;          // 0..2047
    int r = idx >> 4, dq = idx & 15;   // row, float4-index (k = dq*4..+3)
    int bo = (r * 128 + dq * 8) ^ ((r & 7) << 4);

    float4 v = *reinterpret_cast<const float4*>(&h[(size_t)(t0 + r) * DS + dq * 4]);
    unsigned short x0 = f2bf(v.x), x1 = f2bf(v.y), x2 = f2bf(v.z), x3 = f2bf(v.w);
    uint2 hi; hi.x = x0 | ((unsigned)x1 << 16); hi.y = x2 | ((unsigned)x3 << 16);
    *reinterpret_cast<uint2*>((char*)hsh + bo) = hi;
    uint2 lo;
    lo.x = (unsigned)f2bf(v.x - bf2f(x0)) | ((unsigned)f2bf(v.y - bf2f(x1)) << 16);
    lo.y = (unsigned)f2bf(v.z - bf2f(x2)) | ((unsigned)f2bf(v.w - bf2f(x3)) << 16);
    *reinterpret_cast<uint2*>((char*)hsl + bo) = lo;

    float sc = scale[n0 + r];
    float4 w = *reinterpret_cast<const float4*>(&emb[(size_t)(n0 + r) * DS + dq * 4]);
    w.x *= sc; w.y *= sc; w.z *= sc; w.w *= sc;
    unsigned short e0 = f2bf(w.x), e1 = f2bf(w.y), e2 = f2bf(w.z), e3 = f2bf(w.w);
    uint2 ehi; ehi.x = e0 | ((unsigned)e1 << 16); ehi.y = e2 | ((unsigned)e3 << 16);
    *reinterpret_cast<uint2*>((char*)esh + bo) = ehi;
    uint2 elo;
    elo.x = (unsigned)f2bf(w.x - bf2f(e0)) | ((unsigned)f2bf(w.y - bf2f(e1)) << 16);
    elo.y = (unsigned)f2bf(w.z - bf2f(e2)) | ((unsigned)f2bf(w.w - bf2f(e3)) << 16);
    *reinterpret_cast<uint2*>((char*)esl + bo) = elo;
  }
  __syncthreads();

  const int lane = tid & 63;
  const int wv   = tid >> 6;           // wave 0..3 -> tokens [wv*32, wv*32+32)
  const int fr   = lane & 15;          // row/col within 16
  const int oct  = lane >> 4;          // k-octet 0..3

  // A fragments: [i:rowtile][kh], hi & lo
  bf16x8 ah[2][2], al[2][2];
#pragma unroll
  for (int i = 0; i < 2; ++i)
#pragma unroll
    for (int kh = 0; kh < 2; ++kh) {
      int row = wv * 32 + i * 16 + fr;
      int bo = (row * 128 + (kh * 32 + oct * 8) * 2) ^ ((row & 7) << 4);
      ah[i][kh] = *reinterpret_cast<const bf16x8*>((const char*)hsh + bo);
      al[i][kh] = *reinterpret_cast<const bf16x8*>((const char*)hsl + bo);
    }

  f32x4 acc[2][8];
#pragma unroll
  for (int i = 0; i < 2; ++i)
#pragma unroll
    for (int j = 0; j < 8; ++j) acc[i][j] = (f32x4)0.0f;

#pragma unroll
  for (int j = 0; j < 8; ++j) {
    int col = j * 16 + fr;
    bf16x8 bh[2], bl[2];
#pragma unroll
    for (int kh = 0; kh < 2; ++kh) {
      int bo = (col * 128 + (kh * 32 + oct * 8) * 2) ^ ((col & 7) << 4);
      bh[kh] = *reinterpret_cast<const bf16x8*>((const char*)esh + bo);
      bl[kh] = *reinterpret_cast<const bf16x8*>((const char*)esl + bo);
    }
#pragma unroll
    for (int i = 0; i < 2; ++i) {
#pragma unroll
      for (int kh = 0; kh < 2; ++kh) {
        acc[i][j] = __builtin_amdgcn_mfma_f32_16x16x32_bf16(ah[i][kh], bh[kh], acc[i][j], 0, 0, 0);
        acc[i][j] = __builtin_amdgcn_mfma_f32_16x16x32_bf16(ah[i][kh], bl[kh], acc[i][j], 0, 0, 0);
        acc[i][j] = __builtin_amdgcn_mfma_f32_16x16x32_bf16(al[i][kh], bh[kh], acc[i][j], 0, 0, 0);
      }
    }
  }
  // C/D layout: col (neuron) = lane&15, row (token) = oct*4 + reg  [m89]

  if (MODE == 0) {
    float rs[2][4];
#pragma unroll
    for (int i = 0; i < 2; ++i)
#pragma unroll
      for (int r = 0; r < 4; ++r) rs[i][r] = 0.0f;
#pragma unroll
    for (int i = 0; i < 2; ++i)
#pragma unroll
      for (int j = 0; j < 8; ++j)
#pragma unroll
        for (int r = 0; r < 4; ++r) rs[i][r] += __expf(acc[i][j][r]);
    // reduce across the 16 neuron-cols (lanes sharing oct)
#pragma unroll
    for (int m = 1; m < 16; m <<= 1)
#pragma unroll
      for (int i = 0; i < 2; ++i)
#pragma unroll
        for (int r = 0; r < 4; ++r) rs[i][r] += __shfl_xor(rs[i][r], m, 64);
    if (fr == 0) {
#pragma unroll
      for (int i = 0; i < 2; ++i)
#pragma unroll
        for (int r = 0; r < 4; ++r) {
          int t = t0 + wv * 32 + i * 16 + oct * 4 + r;
          Zp[(size_t)t * 64 + cb] = rs[i][r];
        }
    }
  } else {
    const int sl = (cb < 32) ? 0 : ((cb < 48) ? 1 : 2);
    float av[2][4];
#pragma unroll
    for (int i = 0; i < 2; ++i)
#pragma unroll
      for (int r = 0; r < 4; ++r)
        av[i][r] = a[(size_t)sl * TOK + t0 + wv * 32 + i * 16 + oct * 4 + r];
    float cs[8];
#pragma unroll
    for (int j = 0; j < 8; ++j) {
      float s = 0.0f;
#pragma unroll
      for (int i = 0; i < 2; ++i)
#pragma unroll
        for (int r = 0; r < 4; ++r) s = fmaf(av[i][r], __expf(acc[i][j][r]), s);
      cs[j] = s;
    }
    // reduce across token-octets (same col): lanes differing in bits 4,5
#pragma unroll
    for (int j = 0; j < 8; ++j) {
      cs[j] += __shfl_xor(cs[j], 16, 64);
      cs[j] += __shfl_xor(cs[j], 32, 64);
    }
    __syncthreads();
    float* red = reinterpret_cast<float*>(hsh);   // [4 waves][128 cols]
    if (oct == 0) {
#pragma unroll
      for (int j = 0; j < 8; ++j) red[wv * 128 + j * 16 + fr] = cs[j];
    }
    __syncthreads();
    if (tid < 128) {
      float v = red[tid] + red[128 + tid] + red[256 + tid] + red[384 + tid];
      Bp[(size_t)tb * NTOT + n0 + tid] = v;
    }
  }
}

// ---------------------------------------------------------------------------
// K3: combine 64 Zp partials per token into a[slice][t] = imp_t / Z_slice
// ---------------------------------------------------------------------------
__global__ __launch_bounds__(256) void k_a2(const float* __restrict__ Zp,
                                            const float* __restrict__ imp,
                                            float* __restrict__ a) {
  int t = blockIdx.x * 256 + threadIdx.x;
  const float4* zp = reinterpret_cast<const float4*>(&Zp[(size_t)t * 64]);
  float zf = 0.f, zr = 0.f, zt = 0.f;
#pragma unroll
  for (int q = 0; q < 8; ++q)  { float4 v = zp[q]; zf += (v.x + v.y) + (v.z + v.w); }
#pragma unroll
  for (int q = 8; q < 12; ++q) { float4 v = zp[q]; zr += (v.x + v.y) + (v.z + v.w); }
#pragma unroll
  for (int q = 12; q < 16; ++q){ float4 v = zp[q]; zt += (v.x + v.y) + (v.z + v.w); }
  float im = imp[t];
  a[t]           = im / zf;
  a[TOK + t]     = im / zr;
  a[2 * TOK + t] = im / zt;
}

// ---------------------------------------------------------------------------
// K5: per (batch, slice): reduce G partials, top-k, renorm, scatter.
// ---------------------------------------------------------------------------
__global__ __launch_bounds__(256) void k_topk(const float* __restrict__ Bp,
                                              float* __restrict__ out, int G) {
  __shared__ float p[4096];
  __shared__ float rv[256];
  __shared__ int   ri[256];
  __shared__ float vals[8];
  __shared__ int   idxs[8];
  __shared__ float s_inv;

  const int bid = blockIdx.x;
  const int b   = bid / 3;
  const int sl  = bid % 3;
  const int off = (sl == 0) ? 0 : ((sl == 1) ? NF : NF + NR);
  const int N   = (sl == 0) ? NF : NR;
  const int K   = (sl == 0) ? 8 : ((sl == 1) ? 4 : 6);
  const int tid = threadIdx.x;

  for (int i = tid; i < N; i += 256) {
    float v = 0.0f;
    for (int g = 0; g < G; ++g)
      v += Bp[((size_t)(b * G + g)) * NTOT + off + i];
    p[i] = v;
  }
  __syncthreads();

  for (int k = 0; k < K; ++k) {
    float bv = -2.0f;
    int bi = 1 << 30;
    for (int i = tid; i < N; i += 256) {
      float v = p[i];
      if (v > bv) { bv = v; bi = i; }
    }
    rv[tid] = bv; ri[tid] = bi;
    __syncthreads();
    for (int st = 128; st > 0; st >>= 1) {
      if (tid < st) {
        float v2 = rv[tid + st]; int i2 = ri[tid + st];
        if (v2 > rv[tid] || (v2 == rv[tid] && i2 < ri[tid])) {
          rv[tid] = v2; ri[tid] = i2;
        }
      }
      __syncthreads();
    }
    if (tid == 0) {
      vals[k] = rv[0]; idxs[k] = ri[0];
      p[ri[0]] = -1.0f;
    }
    __syncthreads();
  }

  if (tid == 0) {
    float s = 0.0f;
    for (int k = 0; k < K; ++k) s += vals[k];
    s_inv = 1.0f / (s + 1e-8f);
  }
  __syncthreads();

  float* ob = out + (size_t)b * (NF + 2 * NR + NT);
  if (sl == 0) {
    for (int i = tid; i < NF; i += 256) ob[i] = 0.0f;
  } else if (sl == 1) {
    for (int i = tid; i < NR; i += 256) { ob[NF + i] = 0.0f; ob[NF + NR + i] = 0.0f; }
  } else {
    for (int i = tid; i < NT; i += 256) ob[NF + 2 * NR + i] = 0.0f;
  }
  __syncthreads();
  if (tid < K) {
    float v = vals[tid] * s_inv;
    int ix = idxs[tid];
    if (sl == 0) {
      ob[ix] = v;
    } else if (sl == 1) {
      ob[NF + ix] = v;
      ob[NF + NR + ix] = v;
    } else {
      ob[NF + 2 * NR + ix] = v;
    }
  }
}

// ---------------------------------------------------------------------------
extern "C" void kernel_launch(void* const* d_in, const int* in_sizes, int n_in,
                              void* d_out, int out_size, void* d_ws, size_t ws_size,
                              hipStream_t stream) {
  const float* x    = (const float*)d_in[0];   // [B,S,D]
  const float* imp  = (const float*)d_in[1];   // [B,S]
  const float* W    = (const float*)d_in[2];   // [D,DS]
  const float* bias = (const float*)d_in[3];   // [DS]
  const float* emb  = (const float*)d_in[4];   // [NTOT,DS]
  float* out = (float*)d_out;
  float* ws  = (float*)d_ws;

  // workspace layout (floats)
  float* scale = ws;                             // 8192
  float* h     = scale + NTOT;                   // TOK*64
  float* Zp    = h + (size_t)TOK * DS;           // TOK*64
  float* a     = Zp + (size_t)TOK * 64;          // 3*TOK
  float* Bp    = a + 3 * TOK;                    // 128*NTOT

  size_t need = ((size_t)NTOT + (size_t)TOK * DS + (size_t)TOK * 64 +
                 3 * (size_t)TOK + (size_t)128 * NTOT) * sizeof(float);  // ~12.8 MB
  if (ws_size < need) return;

  k_norm<<<NTOT / 4, 256, 0, stream>>>(emb, scale);
  k_h<<<TOK / 64, 256, 0, stream>>>(x, W, bias, h);

  k_zle<0><<<dim3(128, 64), 256, 0, stream>>>(h, emb, scale, nullptr, Zp, nullptr);
  k_a2<<<TOK / 256, 256, 0, stream>>>(Zp, imp, a);
  k_zle<2><<<dim3(128, 64), 256, 0, stream>>>(h, emb, scale, a, nullptr, Bp);
  k_topk<<<12, 256, 0, stream>>>(Bp, out, 32);
}

// Round 5
// 340.793 us; speedup vs baseline: 1.6030x; 1.2417x over previous
//
#include <hip/hip_runtime.h>
#include <math.h>

// Problem constants
#define BATCH 4
#define SEQ   4096
#define DIM   2048
#define DS    64
#define NF    4096
#define NR    2048
#define NT    2048
#define NTOT  8192          // NF+NR+NT
#define TOK   16384         // BATCH*SEQ

typedef __attribute__((ext_vector_type(8))) __bf16 bf16x8;
typedef __attribute__((ext_vector_type(4))) float  f32x4;

static __device__ __forceinline__ unsigned short f2bf(float x) {
  unsigned int u = __float_as_uint(x);
  u += 0x7fffu + ((u >> 16) & 1u);       // round-to-nearest-even
  return (unsigned short)(u >> 16);
}
static __device__ __forceinline__ float bf2f(unsigned int lo16) {
  return __uint_as_float(lo16 << 16);
}

// ---------------------------------------------------------------------------
// P0: normalized emb -> split bf16 (hi, lo), scale pre-applied.
// ---------------------------------------------------------------------------
__global__ __launch_bounds__(256) void k_prep_emb(const float* __restrict__ emb,
                                                  unsigned short* __restrict__ eh,
                                                  unsigned short* __restrict__ el) {
  int row  = blockIdx.x * 4 + (threadIdx.x >> 6);
  int lane = threadIdx.x & 63;
  float v  = emb[(size_t)row * DS + lane];
  float ss = v * v;
#pragma unroll
  for (int m = 32; m >= 1; m >>= 1) ss += __shfl_xor(ss, m, 64);
  float sc = 1.0f / fmaxf(sqrtf(ss), 1e-12f);
  float w  = v * sc;
  unsigned short hi = f2bf(w);
  eh[(size_t)row * DS + lane] = hi;
  el[(size_t)row * DS + lane] = f2bf(w - bf2f(hi));
}

// ---------------------------------------------------------------------------
// P1: W [2048][64] -> transposed split bf16 wt[c][k] (hi, lo)
// ---------------------------------------------------------------------------
__global__ __launch_bounds__(256) void k_prep_w(const float* __restrict__ W,
                                                unsigned short* __restrict__ wth,
                                                unsigned short* __restrict__ wtl) {
  int c = blockIdx.x;
#pragma unroll
  for (int it = 0; it < 8; ++it) {
    int k = threadIdx.x + it * 256;
    float v = W[(size_t)k * DS + c];
    unsigned short hi = f2bf(v);
    wth[(size_t)c * DIM + k] = hi;
    wtl[(size_t)c * DIM + k] = f2bf(v - bf2f(hi));
  }
}

// ---------------------------------------------------------------------------
// K1: h = x @ W + b  (M=16384, K=2048, N=64) via split-bf16 MFMA.
// tile 64 tok x 64 col, K-step 64, double-buffered LDS with reg prefetch.
// 256 thr (4 waves), wave = 16 tok x 64 col. Output: h as bf16 hi/lo pair.
// ---------------------------------------------------------------------------
__global__ __launch_bounds__(256) void k_h(
    const float* __restrict__ x, const unsigned short* __restrict__ wth,
    const unsigned short* __restrict__ wtl, const float* __restrict__ bias,
    unsigned short* __restrict__ hh, unsigned short* __restrict__ hl) {
  __shared__ __align__(16) unsigned short xh[2][64 * 64];   // 8 KB per buf
  __shared__ __align__(16) unsigned short xl[2][64 * 64];
  __shared__ __align__(16) unsigned short wh[2][64 * 64];
  __shared__ __align__(16) unsigned short wl[2][64 * 64];   // total 64 KB
  const int tid  = threadIdx.x;
  const int t0   = blockIdx.x * 64;
  const int lane = tid & 63, wv = tid >> 6;
  const int fr   = lane & 15, oct = lane >> 4;

  float4 xr[4];
  uint4  wr[2][2];

  auto LOADX = [&](int k0) {
#pragma unroll
    for (int it = 0; it < 4; ++it) {
      int idx = tid + it * 256;
      int r = idx >> 4, dq = idx & 15;
      xr[it] = *reinterpret_cast<const float4*>(
          &x[(size_t)(t0 + r) * DIM + k0 + dq * 4]);
    }
#pragma unroll
    for (int it = 0; it < 2; ++it) {
      int idx = tid + it * 256;
      int c = idx >> 3, k8 = idx & 7;
      size_t bo = (size_t)c * (DIM * 2) + (size_t)k0 * 2 + k8 * 16;
      wr[0][it] = *reinterpret_cast<const uint4*>((const char*)wth + bo);
      wr[1][it] = *reinterpret_cast<const uint4*>((const char*)wtl + bo);
    }
  };
  auto STORE = [&](int buf) {
#pragma unroll
    for (int it = 0; it < 4; ++it) {
      int idx = tid + it * 256;
      int r = idx >> 4, dq = idx & 15;
      int bo = (r * 128 + dq * 8) ^ ((r & 7) << 4);
      float4 v = xr[it];
      unsigned short a0 = f2bf(v.x), a1 = f2bf(v.y), a2 = f2bf(v.z), a3 = f2bf(v.w);
      uint2 hi; hi.x = a0 | ((unsigned)a1 << 16); hi.y = a2 | ((unsigned)a3 << 16);
      *reinterpret_cast<uint2*>((char*)xh[buf] + bo) = hi;
      uint2 lo;
      lo.x = (unsigned)f2bf(v.x - bf2f(a0)) | ((unsigned)f2bf(v.y - bf2f(a1)) << 16);
      lo.y = (unsigned)f2bf(v.z - bf2f(a2)) | ((unsigned)f2bf(v.w - bf2f(a3)) << 16);
      *reinterpret_cast<uint2*>((char*)xl[buf] + bo) = lo;
    }
#pragma unroll
    for (int it = 0; it < 2; ++it) {
      int idx = tid + it * 256;
      int c = idx >> 3, k8 = idx & 7;
      int bo = (c * 128 + k8 * 16) ^ ((c & 7) << 4);
      *reinterpret_cast<uint4*>((char*)wh[buf] + bo) = wr[0][it];
      *reinterpret_cast<uint4*>((char*)wl[buf] + bo) = wr[1][it];
    }
  };

  f32x4 acc[4];
#pragma unroll
  for (int j = 0; j < 4; ++j) acc[j] = (f32x4)0.0f;

  LOADX(0);
  for (int s = 0; s < 32; ++s) {
    int buf = s & 1;
    STORE(buf);
    if (s < 31) LOADX((s + 1) * 64);
    __syncthreads();

    bf16x8 ah[2], al[2];
#pragma unroll
    for (int kh = 0; kh < 2; ++kh) {
      int row = wv * 16 + fr;
      int bo = (row * 128 + (kh * 32 + oct * 8) * 2) ^ ((row & 7) << 4);
      ah[kh] = *reinterpret_cast<const bf16x8*>((const char*)xh[buf] + bo);
      al[kh] = *reinterpret_cast<const bf16x8*>((const char*)xl[buf] + bo);
    }
#pragma unroll
    for (int kh = 0; kh < 2; ++kh) {
      bf16x8 bh[4], bl[4];
#pragma unroll
      for (int j = 0; j < 4; ++j) {
        int c = j * 16 + fr;
        int bo = (c * 128 + (kh * 32 + oct * 8) * 2) ^ ((c & 7) << 4);
        bh[j] = *reinterpret_cast<const bf16x8*>((const char*)wh[buf] + bo);
        bl[j] = *reinterpret_cast<const bf16x8*>((const char*)wl[buf] + bo);
      }
#pragma unroll
      for (int j = 0; j < 4; ++j)
        acc[j] = __builtin_amdgcn_mfma_f32_16x16x32_bf16(ah[kh], bh[j], acc[j], 0, 0, 0);
#pragma unroll
      for (int j = 0; j < 4; ++j)
        acc[j] = __builtin_amdgcn_mfma_f32_16x16x32_bf16(ah[kh], bl[j], acc[j], 0, 0, 0);
#pragma unroll
      for (int j = 0; j < 4; ++j)
        acc[j] = __builtin_amdgcn_mfma_f32_16x16x32_bf16(al[kh], bh[j], acc[j], 0, 0, 0);
    }
  }

  // epilogue: C layout col = lane&15, row = oct*4 + reg [m89]
#pragma unroll
  for (int j = 0; j < 4; ++j) {
    int c = j * 16 + fr;
    float bl_ = bias[c];
#pragma unroll
    for (int r = 0; r < 4; ++r) {
      int t = t0 + wv * 16 + oct * 4 + r;
      float v = acc[j][r] + bl_;
      unsigned short hi = f2bf(v);
      hh[(size_t)t * DS + c] = hi;
      hl[(size_t)t * DS + c] = f2bf(v - bf2f(hi));
    }
  }
}

// ---------------------------------------------------------------------------
// K2: logits GEMM via split-bf16 MFMA, fused epilogues.
// block: 128 tok x 512 neurons (4 subtiles of 128), 256 thr (4 waves).
// h tile staged once; e subtiles restaged. All operands pre-split bf16.
// MODE 0: Zp[t*16+cb] = sum_n exp(logit)
// MODE 2: Bp[tb*NTOT+n] = sum_t a[sl][t] * exp(logit)
// ---------------------------------------------------------------------------
template<int MODE>
__global__ __launch_bounds__(256) void k_zle(
    const unsigned short* __restrict__ hh, const unsigned short* __restrict__ hl,
    const unsigned short* __restrict__ eh, const unsigned short* __restrict__ el,
    const float* __restrict__ a, float* __restrict__ Zp, float* __restrict__ Bp) {
  __shared__ __align__(16) unsigned short hsh[128 * 64];   // 16 KB each
  __shared__ __align__(16) unsigned short hsl[128 * 64];
  __shared__ __align__(16) unsigned short esh[128 * 64];
  __shared__ __align__(16) unsigned short esl[128 * 64];
  float* red = reinterpret_cast<float*>(esh);   // 2 KB overlay, MODE2 only
  const int tid = threadIdx.x;
  const int tb  = blockIdx.x;          // token block 0..127
  const int cb  = blockIdx.y;          // 512-neuron block 0..15
  const int t0  = tb * 128;

  // ---- stage h tile (pure copies) ----
#pragma unroll
  for (int it = 0; it < 4; ++it) {
    int idx = tid + it * 256;          // 0..1023 = 128 rows x 8 k8
    int r = idx >> 3, k8 = idx & 7;
    int bo = (r * 128 + k8 * 16) ^ ((r & 7) << 4);
    *reinterpret_cast<uint4*>((char*)hsh + bo) =
        *reinterpret_cast<const uint4*>((const char*)hh + (size_t)(t0 + r) * 128 + k8 * 16);
    *reinterpret_cast<uint4*>((char*)hsl + bo) =
        *reinterpret_cast<const uint4*>((const char*)hl + (size_t)(t0 + r) * 128 + k8 * 16);
  }
  __syncthreads();

  const int lane = tid & 63;
  const int wv   = tid >> 6;
  const int fr   = lane & 15;
  const int oct  = lane >> 4;

  bf16x8 ah[2][2], al[2][2];
#pragma unroll
  for (int i = 0; i < 2; ++i)
#pragma unroll
    for (int kh = 0; kh < 2; ++kh) {
      int row = wv * 32 + i * 16 + fr;
      int bo = (row * 128 + (kh * 32 + oct * 8) * 2) ^ ((row & 7) << 4);
      ah[i][kh] = *reinterpret_cast<const bf16x8*>((const char*)hsh + bo);
      al[i][kh] = *reinterpret_cast<const bf16x8*>((const char*)hsl + bo);
    }

  float av[2][4];
  if (MODE == 2) {
    const int sl = (cb < 8) ? 0 : ((cb < 12) ? 1 : 2);
#pragma unroll
    for (int i = 0; i < 2; ++i)
#pragma unroll
      for (int r = 0; r < 4; ++r)
        av[i][r] = a[(size_t)sl * TOK + t0 + wv * 32 + i * 16 + oct * 4 + r];
  }
  float rs[2][4];
#pragma unroll
  for (int i = 0; i < 2; ++i)
#pragma unroll
    for (int r = 0; r < 4; ++r) rs[i][r] = 0.0f;

  for (int sub = 0; sub < 4; ++sub) {
    const int n0 = cb * 512 + sub * 128;
    // ---- stage e subtile ----
#pragma unroll
    for (int it = 0; it < 4; ++it) {
      int idx = tid + it * 256;
      int r = idx >> 3, k8 = idx & 7;
      int bo = (r * 128 + k8 * 16) ^ ((r & 7) << 4);
      *reinterpret_cast<uint4*>((char*)esh + bo) =
          *reinterpret_cast<const uint4*>((const char*)eh + (size_t)(n0 + r) * 128 + k8 * 16);
      *reinterpret_cast<uint4*>((char*)esl + bo) =
          *reinterpret_cast<const uint4*>((const char*)el + (size_t)(n0 + r) * 128 + k8 * 16);
    }
    __syncthreads();

    f32x4 acc[2][8];
#pragma unroll
    for (int i = 0; i < 2; ++i)
#pragma unroll
      for (int j = 0; j < 8; ++j) acc[i][j] = (f32x4)0.0f;

#pragma unroll
    for (int j = 0; j < 8; ++j) {
      int col = j * 16 + fr;
      bf16x8 bh[2], bl[2];
#pragma unroll
      for (int kh = 0; kh < 2; ++kh) {
        int bo = (col * 128 + (kh * 32 + oct * 8) * 2) ^ ((col & 7) << 4);
        bh[kh] = *reinterpret_cast<const bf16x8*>((const char*)esh + bo);
        bl[kh] = *reinterpret_cast<const bf16x8*>((const char*)esl + bo);
      }
#pragma unroll
      for (int i = 0; i < 2; ++i) {
#pragma unroll
        for (int kh = 0; kh < 2; ++kh) {
          acc[i][j] = __builtin_amdgcn_mfma_f32_16x16x32_bf16(ah[i][kh], bh[kh], acc[i][j], 0, 0, 0);
          acc[i][j] = __builtin_amdgcn_mfma_f32_16x16x32_bf16(ah[i][kh], bl[kh], acc[i][j], 0, 0, 0);
          acc[i][j] = __builtin_amdgcn_mfma_f32_16x16x32_bf16(al[i][kh], bh[kh], acc[i][j], 0, 0, 0);
        }
      }
    }
    // C/D layout: col = lane&15, row = oct*4 + reg [m89]

    if (MODE == 0) {
#pragma unroll
      for (int i = 0; i < 2; ++i)
#pragma unroll
        for (int j = 0; j < 8; ++j)
#pragma unroll
          for (int r = 0; r < 4; ++r) rs[i][r] += __expf(acc[i][j][r]);
      __syncthreads();   // esh reads done before next restage
    } else {
      float cs[8];
#pragma unroll
      for (int j = 0; j < 8; ++j) {
        float s = 0.0f;
#pragma unroll
        for (int i = 0; i < 2; ++i)
#pragma unroll
          for (int r = 0; r < 4; ++r) s = fmaf(av[i][r], __expf(acc[i][j][r]), s);
        cs[j] = s;
      }
#pragma unroll
      for (int j = 0; j < 8; ++j) {
        cs[j] += __shfl_xor(cs[j], 16, 64);
        cs[j] += __shfl_xor(cs[j], 32, 64);
      }
      __syncthreads();                 // all esh reads done
      if (oct == 0) {
#pragma unroll
        for (int j = 0; j < 8; ++j) red[wv * 128 + j * 16 + fr] = cs[j];
      }
      __syncthreads();
      if (tid < 128) {
        float v = red[tid] + red[128 + tid] + red[256 + tid] + red[384 + tid];
        Bp[(size_t)tb * NTOT + n0 + tid] = v;
      }
      __syncthreads();                 // red reads done before next restage
    }
  }

  if (MODE == 0) {
#pragma unroll
    for (int m = 1; m < 16; m <<= 1)
#pragma unroll
      for (int i = 0; i < 2; ++i)
#pragma unroll
        for (int r = 0; r < 4; ++r) rs[i][r] += __shfl_xor(rs[i][r], m, 64);
    if (fr == 0) {
#pragma unroll
      for (int i = 0; i < 2; ++i)
#pragma unroll
        for (int r = 0; r < 4; ++r) {
          int t = t0 + wv * 32 + i * 16 + oct * 4 + r;
          Zp[(size_t)t * 16 + cb] = rs[i][r];
        }
    }
  }
}

// ---------------------------------------------------------------------------
// K3: combine 16 Zp partials per token into a[slice][t] = imp_t / Z_slice
// ---------------------------------------------------------------------------
__global__ __launch_bounds__(256) void k_a2(const float* __restrict__ Zp,
                                            const float* __restrict__ imp,
                                            float* __restrict__ a) {
  int t = blockIdx.x * 256 + threadIdx.x;
  const float4* zp = reinterpret_cast<const float4*>(&Zp[(size_t)t * 16]);
  float4 q0 = zp[0], q1 = zp[1], q2 = zp[2], q3 = zp[3];
  float zf = ((q0.x + q0.y) + (q0.z + q0.w)) + ((q1.x + q1.y) + (q1.z + q1.w));
  float zr = (q2.x + q2.y) + (q2.z + q2.w);
  float zt = (q3.x + q3.y) + (q3.z + q3.w);
  float im = imp[t];
  a[t]           = im / zf;
  a[TOK + t]     = im / zr;
  a[2 * TOK + t] = im / zt;
}

// ---------------------------------------------------------------------------
// K5: per (batch, slice): reduce G partials, top-k, renorm, scatter.
// ---------------------------------------------------------------------------
__global__ __launch_bounds__(256) void k_topk(const float* __restrict__ Bp,
                                              float* __restrict__ out, int G) {
  __shared__ float p[4096];
  __shared__ float rv[256];
  __shared__ int   ri[256];
  __shared__ float vals[8];
  __shared__ int   idxs[8];
  __shared__ float s_inv;

  const int bid = blockIdx.x;
  const int b   = bid / 3;
  const int sl  = bid % 3;
  const int off = (sl == 0) ? 0 : ((sl == 1) ? NF : NF + NR);
  const int N   = (sl == 0) ? NF : NR;
  const int K   = (sl == 0) ? 8 : ((sl == 1) ? 4 : 6);
  const int tid = threadIdx.x;

  for (int i = tid; i < N; i += 256) {
    float v = 0.0f;
    for (int g = 0; g < G; ++g)
      v += Bp[((size_t)(b * G + g)) * NTOT + off + i];
    p[i] = v;
  }
  __syncthreads();

  for (int k = 0; k < K; ++k) {
    float bv = -2.0f;
    int bi = 1 << 30;
    for (int i = tid; i < N; i += 256) {
      float v = p[i];
      if (v > bv) { bv = v; bi = i; }
    }
    rv[tid] = bv; ri[tid] = bi;
    __syncthreads();
    for (int st = 128; st > 0; st >>= 1) {
      if (tid < st) {
        float v2 = rv[tid + st]; int i2 = ri[tid + st];
        if (v2 > rv[tid] || (v2 == rv[tid] && i2 < ri[tid])) {
          rv[tid] = v2; ri[tid] = i2;
        }
      }
      __syncthreads();
    }
    if (tid == 0) {
      vals[k] = rv[0]; idxs[k] = ri[0];
      p[ri[0]] = -1.0f;
    }
    __syncthreads();
  }

  if (tid == 0) {
    float s = 0.0f;
    for (int k = 0; k < K; ++k) s += vals[k];
    s_inv = 1.0f / (s + 1e-8f);
  }
  __syncthreads();

  float* ob = out + (size_t)b * (NF + 2 * NR + NT);
  if (sl == 0) {
    for (int i = tid; i < NF; i += 256) ob[i] = 0.0f;
  } else if (sl == 1) {
    for (int i = tid; i < NR; i += 256) { ob[NF + i] = 0.0f; ob[NF + NR + i] = 0.0f; }
  } else {
    for (int i = tid; i < NT; i += 256) ob[NF + 2 * NR + i] = 0.0f;
  }
  __syncthreads();
  if (tid < K) {
    float v = vals[tid] * s_inv;
    int ix = idxs[tid];
    if (sl == 0) {
      ob[ix] = v;
    } else if (sl == 1) {
      ob[NF + ix] = v;
      ob[NF + NR + ix] = v;
    } else {
      ob[NF + 2 * NR + ix] = v;
    }
  }
}

// ---------------------------------------------------------------------------
extern "C" void kernel_launch(void* const* d_in, const int* in_sizes, int n_in,
                              void* d_out, int out_size, void* d_ws, size_t ws_size,
                              hipStream_t stream) {
  const float* x    = (const float*)d_in[0];   // [B,S,D]
  const float* imp  = (const float*)d_in[1];   // [B,S]
  const float* W    = (const float*)d_in[2];   // [D,DS]
  const float* bias = (const float*)d_in[3];   // [DS]
  const float* emb  = (const float*)d_in[4];   // [NTOT,DS]
  float* out = (float*)d_out;

  // workspace layout
  unsigned short* eh  = (unsigned short*)d_ws;            // NTOT*64
  unsigned short* el  = eh  + (size_t)NTOT * DS;
  unsigned short* wth = el  + (size_t)NTOT * DS;          // 64*2048
  unsigned short* wtl = wth + (size_t)DS * DIM;
  unsigned short* hh  = wtl + (size_t)DS * DIM;           // TOK*64
  unsigned short* hl  = hh  + (size_t)TOK * DS;
  float* Zp = (float*)(hl + (size_t)TOK * DS);            // TOK*16
  float* a  = Zp + (size_t)TOK * 16;                      // 3*TOK
  float* Bp = a + 3 * (size_t)TOK;                        // 128*NTOT

  size_t need = (2 * (size_t)NTOT * DS + 2 * (size_t)DS * DIM +
                 2 * (size_t)TOK * DS) * sizeof(unsigned short) +
                ((size_t)TOK * 16 + 3 * (size_t)TOK + 128 * (size_t)NTOT) * sizeof(float);
  if (ws_size < need) return;   // ~12.3 MB

  k_prep_emb<<<NTOT / 4, 256, 0, stream>>>(emb, eh, el);
  k_prep_w<<<DS, 256, 0, stream>>>(W, wth, wtl);
  k_h<<<TOK / 64, 256, 0, stream>>>(x, wth, wtl, bias, hh, hl);

  k_zle<0><<<dim3(128, 16), 256, 0, stream>>>(hh, hl, eh, el, nullptr, Zp, nullptr);
  k_a2<<<TOK / 256, 256, 0, stream>>>(Zp, imp, a);
  k_zle<2><<<dim3(128, 16), 256, 0, stream>>>(hh, hl, eh, el, a, nullptr, Bp);
  k_topk<<<12, 256, 0, stream>>>(Bp, out, 32);
}

// Round 6
// 221.262 us; speedup vs baseline: 2.4689x; 1.5402x over previous
//
#include <hip/hip_runtime.h>
#include <math.h>

// Problem constants
#define BATCH 4
#define SEQ   4096
#define DIM   2048
#define DS    64
#define NF    4096
#define NR    2048
#define NT    2048
#define NTOT  8192          // NF+NR+NT
#define TOK   16384         // BATCH*SEQ

typedef __attribute__((ext_vector_type(8))) __bf16 bf16x8;
typedef __attribute__((ext_vector_type(4))) float  f32x4;

static __device__ __forceinline__ unsigned short f2bf(float x) {
  unsigned int u = __float_as_uint(x);
  u += 0x7fffu + ((u >> 16) & 1u);       // round-to-nearest-even
  return (unsigned short)(u >> 16);
}
static __device__ __forceinline__ float bf2f(unsigned int lo16) {
  return __uint_as_float(lo16 << 16);
}

// ---------------------------------------------------------------------------
// P0: normalized emb -> split bf16 (hi, lo), scale pre-applied.
// ---------------------------------------------------------------------------
__global__ __launch_bounds__(256) void k_prep_emb(const float* __restrict__ emb,
                                                  unsigned short* __restrict__ eh,
                                                  unsigned short* __restrict__ el) {
  int row  = blockIdx.x * 4 + (threadIdx.x >> 6);
  int lane = threadIdx.x & 63;
  float v  = emb[(size_t)row * DS + lane];
  float ss = v * v;
#pragma unroll
  for (int m = 32; m >= 1; m >>= 1) ss += __shfl_xor(ss, m, 64);
  float sc = 1.0f / fmaxf(sqrtf(ss), 1e-12f);
  float w  = v * sc;
  unsigned short hi = f2bf(w);
  eh[(size_t)row * DS + lane] = hi;
  el[(size_t)row * DS + lane] = f2bf(w - bf2f(hi));
}

// ---------------------------------------------------------------------------
// P1: W [2048][64] -> transposed split bf16 wt[c][k] (hi, lo)
// ---------------------------------------------------------------------------
__global__ __launch_bounds__(256) void k_prep_w(const float* __restrict__ W,
                                                unsigned short* __restrict__ wth,
                                                unsigned short* __restrict__ wtl) {
  int c = blockIdx.x;
#pragma unroll
  for (int it = 0; it < 8; ++it) {
    int k = threadIdx.x + it * 256;
    float v = W[(size_t)k * DS + c];
    unsigned short hi = f2bf(v);
    wth[(size_t)c * DIM + k] = hi;
    wtl[(size_t)c * DIM + k] = f2bf(v - bf2f(hi));
  }
}

// ---------------------------------------------------------------------------
// K1: h = x @ W + b  (M=16384, K=2048, N=64) via split-bf16 MFMA.
// tile 64 tok x 64 col, K-step 64, double-buffered LDS with reg prefetch.
// 256 thr (4 waves), wave = 16 tok x 64 col. Output: h as bf16 hi/lo pair.
// ---------------------------------------------------------------------------
__global__ __launch_bounds__(256) void k_h(
    const float* __restrict__ x, const unsigned short* __restrict__ wth,
    const unsigned short* __restrict__ wtl, const float* __restrict__ bias,
    unsigned short* __restrict__ hh, unsigned short* __restrict__ hl) {
  __shared__ __align__(16) unsigned short xh[2][64 * 64];   // 8 KB per buf
  __shared__ __align__(16) unsigned short xl[2][64 * 64];
  __shared__ __align__(16) unsigned short wh[2][64 * 64];
  __shared__ __align__(16) unsigned short wl[2][64 * 64];   // total 64 KB
  const int tid  = threadIdx.x;
  const int t0   = blockIdx.x * 64;
  const int lane = tid & 63, wv = tid >> 6;
  const int fr   = lane & 15, oct = lane >> 4;

  float4 xr[4];
  uint4  wr[2][2];

  auto LOADX = [&](int k0) {
#pragma unroll
    for (int it = 0; it < 4; ++it) {
      int idx = tid + it * 256;
      int r = idx >> 4, dq = idx & 15;
      xr[it] = *reinterpret_cast<const float4*>(
          &x[(size_t)(t0 + r) * DIM + k0 + dq * 4]);
    }
#pragma unroll
    for (int it = 0; it < 2; ++it) {
      int idx = tid + it * 256;
      int c = idx >> 3, k8 = idx & 7;
      size_t bo = (size_t)c * (DIM * 2) + (size_t)k0 * 2 + k8 * 16;
      wr[0][it] = *reinterpret_cast<const uint4*>((const char*)wth + bo);
      wr[1][it] = *reinterpret_cast<const uint4*>((const char*)wtl + bo);
    }
  };
  auto STORE = [&](int buf) {
#pragma unroll
    for (int it = 0; it < 4; ++it) {
      int idx = tid + it * 256;
      int r = idx >> 4, dq = idx & 15;
      int bo = (r * 128 + dq * 8) ^ ((r & 7) << 4);
      float4 v = xr[it];
      unsigned short a0 = f2bf(v.x), a1 = f2bf(v.y), a2 = f2bf(v.z), a3 = f2bf(v.w);
      uint2 hi; hi.x = a0 | ((unsigned)a1 << 16); hi.y = a2 | ((unsigned)a3 << 16);
      *reinterpret_cast<uint2*>((char*)xh[buf] + bo) = hi;
      uint2 lo;
      lo.x = (unsigned)f2bf(v.x - bf2f(a0)) | ((unsigned)f2bf(v.y - bf2f(a1)) << 16);
      lo.y = (unsigned)f2bf(v.z - bf2f(a2)) | ((unsigned)f2bf(v.w - bf2f(a3)) << 16);
      *reinterpret_cast<uint2*>((char*)xl[buf] + bo) = lo;
    }
#pragma unroll
    for (int it = 0; it < 2; ++it) {
      int idx = tid + it * 256;
      int c = idx >> 3, k8 = idx & 7;
      int bo = (c * 128 + k8 * 16) ^ ((c & 7) << 4);
      *reinterpret_cast<uint4*>((char*)wh[buf] + bo) = wr[0][it];
      *reinterpret_cast<uint4*>((char*)wl[buf] + bo) = wr[1][it];
    }
  };

  f32x4 acc[4];
#pragma unroll
  for (int j = 0; j < 4; ++j) acc[j] = (f32x4)0.0f;

  LOADX(0);
  for (int s = 0; s < 32; ++s) {
    int buf = s & 1;
    STORE(buf);
    if (s < 31) LOADX((s + 1) * 64);
    __syncthreads();

    bf16x8 ah[2], al[2];
#pragma unroll
    for (int kh = 0; kh < 2; ++kh) {
      int row = wv * 16 + fr;
      int bo = (row * 128 + (kh * 32 + oct * 8) * 2) ^ ((row & 7) << 4);
      ah[kh] = *reinterpret_cast<const bf16x8*>((const char*)xh[buf] + bo);
      al[kh] = *reinterpret_cast<const bf16x8*>((const char*)xl[buf] + bo);
    }
#pragma unroll
    for (int kh = 0; kh < 2; ++kh) {
      bf16x8 bh[4], bl[4];
#pragma unroll
      for (int j = 0; j < 4; ++j) {
        int c = j * 16 + fr;
        int bo = (c * 128 + (kh * 32 + oct * 8) * 2) ^ ((c & 7) << 4);
        bh[j] = *reinterpret_cast<const bf16x8*>((const char*)wh[buf] + bo);
        bl[j] = *reinterpret_cast<const bf16x8*>((const char*)wl[buf] + bo);
      }
#pragma unroll
      for (int j = 0; j < 4; ++j)
        acc[j] = __builtin_amdgcn_mfma_f32_16x16x32_bf16(ah[kh], bh[j], acc[j], 0, 0, 0);
#pragma unroll
      for (int j = 0; j < 4; ++j)
        acc[j] = __builtin_amdgcn_mfma_f32_16x16x32_bf16(ah[kh], bl[j], acc[j], 0, 0, 0);
#pragma unroll
      for (int j = 0; j < 4; ++j)
        acc[j] = __builtin_amdgcn_mfma_f32_16x16x32_bf16(al[kh], bh[j], acc[j], 0, 0, 0);
    }
  }

  // epilogue: C layout col = lane&15, row = oct*4 + reg [m89]
#pragma unroll
  for (int j = 0; j < 4; ++j) {
    int c = j * 16 + fr;
    float bl_ = bias[c];
#pragma unroll
    for (int r = 0; r < 4; ++r) {
      int t = t0 + wv * 16 + oct * 4 + r;
      float v = acc[j][r] + bl_;
      unsigned short hi = f2bf(v);
      hh[(size_t)t * DS + c] = hi;
      hl[(size_t)t * DS + c] = f2bf(v - bf2f(hi));
    }
  }
}

// ---------------------------------------------------------------------------
// K2: logits GEMM via split-bf16 MFMA, fused epilogues.
// block: 128 tok x 512 neurons (4 subtiles of 128), 256 thr (4 waves).
// MODE 0: Zp[t*16+cb] = sum_n exp(logit)
// MODE 2: Bp[tb*NTOT+n] = sum_t a[sl][t] * exp(logit)
// ---------------------------------------------------------------------------
template<int MODE>
__global__ __launch_bounds__(256) void k_zle(
    const unsigned short* __restrict__ hh, const unsigned short* __restrict__ hl,
    const unsigned short* __restrict__ eh, const unsigned short* __restrict__ el,
    const float* __restrict__ a, float* __restrict__ Zp, float* __restrict__ Bp) {
  __shared__ __align__(16) unsigned short hsh[128 * 64];   // 16 KB each
  __shared__ __align__(16) unsigned short hsl[128 * 64];
  __shared__ __align__(16) unsigned short esh[128 * 64];
  __shared__ __align__(16) unsigned short esl[128 * 64];
  float* red = reinterpret_cast<float*>(esh);   // 2 KB overlay, MODE2 only
  const int tid = threadIdx.x;
  const int tb  = blockIdx.x;          // token block 0..127
  const int cb  = blockIdx.y;          // 512-neuron block 0..15
  const int t0  = tb * 128;

  // ---- stage h tile (pure copies) ----
#pragma unroll
  for (int it = 0; it < 4; ++it) {
    int idx = tid + it * 256;          // 0..1023 = 128 rows x 8 k8
    int r = idx >> 3, k8 = idx & 7;
    int bo = (r * 128 + k8 * 16) ^ ((r & 7) << 4);
    *reinterpret_cast<uint4*>((char*)hsh + bo) =
        *reinterpret_cast<const uint4*>((const char*)hh + (size_t)(t0 + r) * 128 + k8 * 16);
    *reinterpret_cast<uint4*>((char*)hsl + bo) =
        *reinterpret_cast<const uint4*>((const char*)hl + (size_t)(t0 + r) * 128 + k8 * 16);
  }
  __syncthreads();

  const int lane = tid & 63;
  const int wv   = tid >> 6;
  const int fr   = lane & 15;
  const int oct  = lane >> 4;

  bf16x8 ah[2][2], al[2][2];
#pragma unroll
  for (int i = 0; i < 2; ++i)
#pragma unroll
    for (int kh = 0; kh < 2; ++kh) {
      int row = wv * 32 + i * 16 + fr;
      int bo = (row * 128 + (kh * 32 + oct * 8) * 2) ^ ((row & 7) << 4);
      ah[i][kh] = *reinterpret_cast<const bf16x8*>((const char*)hsh + bo);
      al[i][kh] = *reinterpret_cast<const bf16x8*>((const char*)hsl + bo);
    }

  float av[2][4];
  if (MODE == 2) {
    const int sl = (cb < 8) ? 0 : ((cb < 12) ? 1 : 2);
#pragma unroll
    for (int i = 0; i < 2; ++i)
#pragma unroll
      for (int r = 0; r < 4; ++r)
        av[i][r] = a[(size_t)sl * TOK + t0 + wv * 32 + i * 16 + oct * 4 + r];
  }
  float rs[2][4];
#pragma unroll
  for (int i = 0; i < 2; ++i)
#pragma unroll
    for (int r = 0; r < 4; ++r) rs[i][r] = 0.0f;

  for (int sub = 0; sub < 4; ++sub) {
    const int n0 = cb * 512 + sub * 128;
    // ---- stage e subtile ----
#pragma unroll
    for (int it = 0; it < 4; ++it) {
      int idx = tid + it * 256;
      int r = idx >> 3, k8 = idx & 7;
      int bo = (r * 128 + k8 * 16) ^ ((r & 7) << 4);
      *reinterpret_cast<uint4*>((char*)esh + bo) =
          *reinterpret_cast<const uint4*>((const char*)eh + (size_t)(n0 + r) * 128 + k8 * 16);
      *reinterpret_cast<uint4*>((char*)esl + bo) =
          *reinterpret_cast<const uint4*>((const char*)el + (size_t)(n0 + r) * 128 + k8 * 16);
    }
    __syncthreads();

    f32x4 acc[2][8];
#pragma unroll
    for (int i = 0; i < 2; ++i)
#pragma unroll
      for (int j = 0; j < 8; ++j) acc[i][j] = (f32x4)0.0f;

#pragma unroll
    for (int j = 0; j < 8; ++j) {
      int col = j * 16 + fr;
      bf16x8 bh[2], bl[2];
#pragma unroll
      for (int kh = 0; kh < 2; ++kh) {
        int bo = (col * 128 + (kh * 32 + oct * 8) * 2) ^ ((col & 7) << 4);
        bh[kh] = *reinterpret_cast<const bf16x8*>((const char*)esh + bo);
        bl[kh] = *reinterpret_cast<const bf16x8*>((const char*)esl + bo);
      }
#pragma unroll
      for (int i = 0; i < 2; ++i) {
#pragma unroll
        for (int kh = 0; kh < 2; ++kh) {
          acc[i][j] = __builtin_amdgcn_mfma_f32_16x16x32_bf16(ah[i][kh], bh[kh], acc[i][j], 0, 0, 0);
          acc[i][j] = __builtin_amdgcn_mfma_f32_16x16x32_bf16(ah[i][kh], bl[kh], acc[i][j], 0, 0, 0);
          acc[i][j] = __builtin_amdgcn_mfma_f32_16x16x32_bf16(al[i][kh], bh[kh], acc[i][j], 0, 0, 0);
        }
      }
    }
    // C/D layout: col = lane&15, row = oct*4 + reg [m89]

    if (MODE == 0) {
#pragma unroll
      for (int i = 0; i < 2; ++i)
#pragma unroll
        for (int j = 0; j < 8; ++j)
#pragma unroll
          for (int r = 0; r < 4; ++r) rs[i][r] += __expf(acc[i][j][r]);
      __syncthreads();   // esh reads done before next restage
    } else {
      float cs[8];
#pragma unroll
      for (int j = 0; j < 8; ++j) {
        float s = 0.0f;
#pragma unroll
        for (int i = 0; i < 2; ++i)
#pragma unroll
          for (int r = 0; r < 4; ++r) s = fmaf(av[i][r], __expf(acc[i][j][r]), s);
        cs[j] = s;
      }
#pragma unroll
      for (int j = 0; j < 8; ++j) {
        cs[j] += __shfl_xor(cs[j], 16, 64);
        cs[j] += __shfl_xor(cs[j], 32, 64);
      }
      __syncthreads();                 // all esh reads done
      if (oct == 0) {
#pragma unroll
        for (int j = 0; j < 8; ++j) red[wv * 128 + j * 16 + fr] = cs[j];
      }
      __syncthreads();
      if (tid < 128) {
        float v = red[tid] + red[128 + tid] + red[256 + tid] + red[384 + tid];
        Bp[(size_t)tb * NTOT + n0 + tid] = v;
      }
      __syncthreads();                 // red reads done before next restage
    }
  }

  if (MODE == 0) {
#pragma unroll
    for (int m = 1; m < 16; m <<= 1)
#pragma unroll
      for (int i = 0; i < 2; ++i)
#pragma unroll
        for (int r = 0; r < 4; ++r) rs[i][r] += __shfl_xor(rs[i][r], m, 64);
    if (fr == 0) {
#pragma unroll
      for (int i = 0; i < 2; ++i)
#pragma unroll
        for (int r = 0; r < 4; ++r) {
          int t = t0 + wv * 32 + i * 16 + oct * 4 + r;
          Zp[(size_t)t * 16 + cb] = rs[i][r];
        }
    }
  }
}

// ---------------------------------------------------------------------------
// K3: combine 16 Zp partials per token into a[slice][t] = imp_t / Z_slice
// ---------------------------------------------------------------------------
__global__ __launch_bounds__(256) void k_a2(const float* __restrict__ Zp,
                                            const float* __restrict__ imp,
                                            float* __restrict__ a) {
  int t = blockIdx.x * 256 + threadIdx.x;
  const float4* zp = reinterpret_cast<const float4*>(&Zp[(size_t)t * 16]);
  float4 q0 = zp[0], q1 = zp[1], q2 = zp[2], q3 = zp[3];
  float zf = ((q0.x + q0.y) + (q0.z + q0.w)) + ((q1.x + q1.y) + (q1.z + q1.w));
  float zr = (q2.x + q2.y) + (q2.z + q2.w);
  float zt = (q3.x + q3.y) + (q3.z + q3.w);
  float im = imp[t];
  a[t]           = im / zf;
  a[TOK + t]     = im / zr;
  a[2 * TOK + t] = im / zt;
}

// ---------------------------------------------------------------------------
// K4: reduce the 32 token-block partials -> pooled[b][n].
// Compile-time-unrolled 32 independent loads per thread (full MLP).
// ---------------------------------------------------------------------------
__global__ __launch_bounds__(256) void k_red(const float* __restrict__ Bp,
                                             float* __restrict__ pooled) {
  int idx = blockIdx.x * 256 + threadIdx.x;   // 0 .. BATCH*NTOT-1
  int b = idx >> 13;                          // /NTOT
  int n = idx & (NTOT - 1);
  const float* src = Bp + (size_t)(b * 32) * NTOT + n;
  float s = 0.0f;
#pragma unroll
  for (int g = 0; g < 32; ++g) s += src[(size_t)g * NTOT];
  pooled[idx] = s;
}

// ---------------------------------------------------------------------------
// K5: per (batch, slice): top-k over pooled, renorm, scatter.
// ---------------------------------------------------------------------------
__global__ __launch_bounds__(256) void k_topk(const float* __restrict__ pooled,
                                              float* __restrict__ out) {
  __shared__ float p[4096];
  __shared__ float rv[256];
  __shared__ int   ri[256];
  __shared__ float vals[8];
  __shared__ int   idxs[8];
  __shared__ float s_inv;

  const int bid = blockIdx.x;
  const int b   = bid / 3;
  const int sl  = bid % 3;
  const int off = (sl == 0) ? 0 : ((sl == 1) ? NF : NF + NR);
  const int N   = (sl == 0) ? NF : NR;
  const int K   = (sl == 0) ? 8 : ((sl == 1) ? 4 : 6);
  const int tid = threadIdx.x;

  for (int i = tid; i < N; i += 256)
    p[i] = pooled[(size_t)b * NTOT + off + i];
  __syncthreads();

  for (int k = 0; k < K; ++k) {
    float bv = -2.0f;
    int bi = 1 << 30;
    for (int i = tid; i < N; i += 256) {
      float v = p[i];
      if (v > bv) { bv = v; bi = i; }
    }
    rv[tid] = bv; ri[tid] = bi;
    __syncthreads();
    for (int st = 128; st > 0; st >>= 1) {
      if (tid < st) {
        float v2 = rv[tid + st]; int i2 = ri[tid + st];
        if (v2 > rv[tid] || (v2 == rv[tid] && i2 < ri[tid])) {
          rv[tid] = v2; ri[tid] = i2;
        }
      }
      __syncthreads();
    }
    if (tid == 0) {
      vals[k] = rv[0]; idxs[k] = ri[0];
      p[ri[0]] = -1.0f;
    }
    __syncthreads();
  }

  if (tid == 0) {
    float s = 0.0f;
    for (int k = 0; k < K; ++k) s += vals[k];
    s_inv = 1.0f / (s + 1e-8f);
  }
  __syncthreads();

  float* ob = out + (size_t)b * (NF + 2 * NR + NT);
  if (sl == 0) {
    for (int i = tid; i < NF; i += 256) ob[i] = 0.0f;
  } else if (sl == 1) {
    for (int i = tid; i < NR; i += 256) { ob[NF + i] = 0.0f; ob[NF + NR + i] = 0.0f; }
  } else {
    for (int i = tid; i < NT; i += 256) ob[NF + 2 * NR + i] = 0.0f;
  }
  __syncthreads();
  if (tid < K) {
    float v = vals[tid] * s_inv;
    int ix = idxs[tid];
    if (sl == 0) {
      ob[ix] = v;
    } else if (sl == 1) {
      ob[NF + ix] = v;
      ob[NF + NR + ix] = v;
    } else {
      ob[NF + 2 * NR + ix] = v;
    }
  }
}

// ---------------------------------------------------------------------------
extern "C" void kernel_launch(void* const* d_in, const int* in_sizes, int n_in,
                              void* d_out, int out_size, void* d_ws, size_t ws_size,
                              hipStream_t stream) {
  const float* x    = (const float*)d_in[0];   // [B,S,D]
  const float* imp  = (const float*)d_in[1];   // [B,S]
  const float* W    = (const float*)d_in[2];   // [D,DS]
  const float* bias = (const float*)d_in[3];   // [DS]
  const float* emb  = (const float*)d_in[4];   // [NTOT,DS]
  float* out = (float*)d_out;

  // workspace layout
  unsigned short* eh  = (unsigned short*)d_ws;            // NTOT*64
  unsigned short* el  = eh  + (size_t)NTOT * DS;
  unsigned short* wth = el  + (size_t)NTOT * DS;          // 64*2048
  unsigned short* wtl = wth + (size_t)DS * DIM;
  unsigned short* hh  = wtl + (size_t)DS * DIM;           // TOK*64
  unsigned short* hl  = hh  + (size_t)TOK * DS;
  float* Zp     = (float*)(hl + (size_t)TOK * DS);        // TOK*16
  float* a      = Zp + (size_t)TOK * 16;                  // 3*TOK
  float* Bp     = a + 3 * (size_t)TOK;                    // 128*NTOT
  float* pooled = Bp + (size_t)128 * NTOT;                // 4*NTOT

  size_t need = (2 * (size_t)NTOT * DS + 2 * (size_t)DS * DIM +
                 2 * (size_t)TOK * DS) * sizeof(unsigned short) +
                ((size_t)TOK * 16 + 3 * (size_t)TOK + 128 * (size_t)NTOT +
                 (size_t)BATCH * NTOT) * sizeof(float);
  if (ws_size < need) return;   // ~12.4 MB

  k_prep_emb<<<NTOT / 4, 256, 0, stream>>>(emb, eh, el);
  k_prep_w<<<DS, 256, 0, stream>>>(W, wth, wtl);
  k_h<<<TOK / 64, 256, 0, stream>>>(x, wth, wtl, bias, hh, hl);

  k_zle<0><<<dim3(128, 16), 256, 0, stream>>>(hh, hl, eh, el, nullptr, Zp, nullptr);
  k_a2<<<TOK / 256, 256, 0, stream>>>(Zp, imp, a);
  k_zle<2><<<dim3(128, 16), 256, 0, stream>>>(hh, hl, eh, el, a, nullptr, Bp);
  k_red<<<(BATCH * NTOT) / 256, 256, 0, stream>>>(Bp, pooled);
  k_topk<<<12, 256, 0, stream>>>(pooled, out);
}